// Round 8
// baseline (1325.428 us; speedup 1.0000x reference)
//
#include <hip/hip_runtime.h>

#define DIM  1024
#define HID  2048
#define OUTD 1024
#define NE   8
#define NTOK 4096

using bf16x8 = __attribute__((ext_vector_type(8))) short;
using f32x4  = __attribute__((ext_vector_type(4))) float;

__device__ __forceinline__ unsigned short f2bf(float f) {
  unsigned int u = __builtin_bit_cast(unsigned int, f);
  u += 0x7fff + ((u >> 16) & 1);   // round-to-nearest-even
  return (unsigned short)(u >> 16);
}

__device__ __forceinline__ void gload16(const void* g, void* l) {
  __builtin_amdgcn_global_load_lds(
      (const __attribute__((address_space(1))) void*)g,
      (__attribute__((address_space(3))) void*)l, 16, 0, 0);
}

#define BARR __builtin_amdgcn_s_barrier()
#define VMC0 asm volatile("s_waitcnt vmcnt(0)" ::: "memory")

// ---------------- transpose + cast: in [R][C] fp32 -> out [C][R] bf16 ----------------
__global__ void tcast_kernel(const float* __restrict__ in,
                             unsigned short* __restrict__ out, int R, int C) {
  __shared__ float tile[32][33];
  size_t zo = (size_t)blockIdx.z * R * C;
  int c0 = blockIdx.x * 32, r0 = blockIdx.y * 32;
  int tx = threadIdx.x & 31, ty = threadIdx.x >> 5;
#pragma unroll
  for (int j = 0; j < 4; j++) {
    int r = ty + j * 8;
    tile[r][tx] = in[zo + (size_t)(r0 + r) * C + c0 + tx];
  }
  __syncthreads();
  int c = threadIdx.x >> 3, q = threadIdx.x & 7;
  ushort4 u;
  u.x = f2bf(tile[q * 4 + 0][c]); u.y = f2bf(tile[q * 4 + 1][c]);
  u.z = f2bf(tile[q * 4 + 2][c]); u.w = f2bf(tile[q * 4 + 3][c]);
  *(ushort4*)&out[zo + (size_t)(c0 + c) * R + r0 + q * 4] = u;
}

// ---- transpose+cast W1/W3 [NE][DIM][HID] -> interleaved W13t [NE][2*HID][DIM]
__global__ void tcast_i_kernel(const float* __restrict__ W1,
                               const float* __restrict__ W3,
                               unsigned short* __restrict__ out) {
  __shared__ float tile[32][33];
  int z = blockIdx.z, e = z & 7, s = z >> 3;
  const float* inp = (s ? W3 : W1) + (size_t)e * DIM * HID;
  unsigned short* op = out + (size_t)e * 2 * HID * DIM;
  int c0 = blockIdx.x * 32, r0 = blockIdx.y * 32;
  int tx = threadIdx.x & 31, ty = threadIdx.x >> 5;
#pragma unroll
  for (int j = 0; j < 4; j++) {
    int r = ty + j * 8;
    tile[r][tx] = inp[(size_t)(r0 + r) * HID + c0 + tx];
  }
  __syncthreads();
  int c = threadIdx.x >> 3, q = threadIdx.x & 7;
  int h = c0 + c;
  int orow = 32 * (h >> 4) + 16 * s + (h & 15);
  ushort4 u;
  u.x = f2bf(tile[q * 4 + 0][c]); u.y = f2bf(tile[q * 4 + 1][c]);
  u.z = f2bf(tile[q * 4 + 2][c]); u.w = f2bf(tile[q * 4 + 3][c]);
  *(ushort4*)&op[(size_t)orow * DIM + r0 + q * 4] = u;
}

// ---------------- gating + fused X cast + per-block histogram ----------------
__global__ __launch_bounds__(256) void gating_kernel(
    const float* __restrict__ X, const float* __restrict__ Wg,
    const float* __restrict__ bg, unsigned short* __restrict__ Xb,
    int* __restrict__ topk_pack, float* __restrict__ topk_w,
    int* __restrict__ blkcnt) {
  __shared__ float wgs[NE][DIM];
  __shared__ int hist[NE];
  const int tid = threadIdx.x;
  for (int d = tid; d < DIM; d += 256) {
#pragma unroll
    for (int e = 0; e < NE; e++) wgs[e][d] = Wg[d * NE + e];
  }
  if (tid < NE) hist[tid] = 0;
  __syncthreads();
  const int wave = tid >> 6, lane = tid & 63;
  for (int tk = wave; tk < 32; tk += 4) {
    const int t = blockIdx.x * 32 + tk;
    const float* xr = X + (size_t)t * DIM;
    {
      const float4* xp = (const float4*)(xr + lane * 16);
      float4 v0 = xp[0], v1 = xp[1], v2 = xp[2], v3 = xp[3];
      uint4 w0, w1;
      w0.x = f2bf(v0.x) | ((unsigned)f2bf(v0.y) << 16);
      w0.y = f2bf(v0.z) | ((unsigned)f2bf(v0.w) << 16);
      w0.z = f2bf(v1.x) | ((unsigned)f2bf(v1.y) << 16);
      w0.w = f2bf(v1.z) | ((unsigned)f2bf(v1.w) << 16);
      w1.x = f2bf(v2.x) | ((unsigned)f2bf(v2.y) << 16);
      w1.y = f2bf(v2.z) | ((unsigned)f2bf(v2.w) << 16);
      w1.z = f2bf(v3.x) | ((unsigned)f2bf(v3.y) << 16);
      w1.w = f2bf(v3.z) | ((unsigned)f2bf(v3.w) << 16);
      uint4* op2 = (uint4*)(Xb + (size_t)t * DIM + lane * 16);
      op2[0] = w0; op2[1] = w1;
    }
    float acc[NE];
#pragma unroll
    for (int e = 0; e < NE; e++) acc[e] = 0.f;
#pragma unroll
    for (int j = 0; j < 16; j++) {
      float xv = xr[lane + j * 64];
#pragma unroll
      for (int e = 0; e < NE; e++) acc[e] += xv * wgs[e][lane + j * 64];
    }
#pragma unroll
    for (int e = 0; e < NE; e++) {
#pragma unroll
      for (int off = 32; off > 0; off >>= 1) acc[e] += __shfl_xor(acc[e], off, 64);
    }
    if (lane == 0) {
      float p[NE];
      float mx = -1e30f;
#pragma unroll
      for (int e = 0; e < NE; e++) { p[e] = acc[e] + bg[e]; mx = fmaxf(mx, p[e]); }
      float sum = 0.f;
#pragma unroll
      for (int e = 0; e < NE; e++) { p[e] = expf(p[e] - mx); sum += p[e]; }
      float inv = 1.f / sum;
#pragma unroll
      for (int e = 0; e < NE; e++) p[e] *= inv;
      int i1 = 0; float v1 = p[0];
#pragma unroll
      for (int e = 1; e < NE; e++) if (p[e] >= v1) { v1 = p[e]; i1 = e; }
      int i2 = (i1 == 0) ? 1 : 0; float v2 = p[i2];
#pragma unroll
      for (int e = 0; e < NE; e++) {
        if (e == i1) continue;
        if (p[e] >= v2 && e != i2) { v2 = p[e]; i2 = e; }
      }
      topk_pack[t] = i1 | (i2 << 4);
      topk_w[t * 2 + 0] = v1; topk_w[t * 2 + 1] = v2;
      atomicAdd(&hist[i1], 1); atomicAdd(&hist[i2], 1);
    }
  }
  __syncthreads();
  if (tid < NE) blkcnt[blockIdx.x * NE + tid] = hist[tid];
}

// ---------------- scatter with integrated prefix (redundant per-block scan) ----------------
__global__ void scatter_kernel(const int* __restrict__ blkcnt,
                               const int* __restrict__ topk_pack,
                               int* __restrict__ counts, int* __restrict__ row_start,
                               int* __restrict__ tp, int* __restrict__ list) {
  __shared__ int lofs[NE];
  const int lane = threadIdx.x;   // 64
  const int myb = blockIdx.x;     // 128
  int s = 0, t = 0;
#pragma unroll
  for (int e = 0; e < NE; e++) {
    int c0 = blkcnt[lane * NE + e], c1 = blkcnt[(lane + 64) * NE + e];
    int tote = c0 + c1;
    int pre = (lane < myb ? c0 : 0) + (lane + 64 < myb ? c1 : 0);
#pragma unroll
    for (int off = 32; off > 0; off >>= 1) {
      tote += __shfl_xor(tote, off, 64);
      pre  += __shfl_xor(pre,  off, 64);
    }
    if (lane == 0) lofs[e] = s + pre;
    if (myb == 0 && lane == 0) { counts[e] = tote; row_start[e] = s; tp[e] = t; }
    s += tote; t += (tote + 127) >> 7;
  }
  if (myb == 0 && lane == 0) tp[NE] = t;
  __syncthreads();
  if (lane < 32) {
    int tok = myb * 32 + lane;
    int pk = topk_pack[tok];
    int e1 = pk & 15, e2 = (pk >> 4) & 15;
    int p1 = atomicAdd(&lofs[e1], 1); list[p1] = tok << 1;
    int p2 = atomicAdd(&lofs[e2], 1); list[p2] = (tok << 1) | 1;
  }
}

// ============ stage A: tile 128x256, 4 waves (per-wave 64x128), BK=32, dbuf ============
__global__ __launch_bounds__(256, 3) void ffn_a_kernel(
    const unsigned short* __restrict__ Xb,
    const unsigned short* __restrict__ W13t,
    const float* __restrict__ b1, const float* __restrict__ b3,
    const int* __restrict__ counts, const int* __restrict__ row_start,
    const int* __restrict__ tp, const int* __restrict__ list,
    unsigned short* __restrict__ h_buf) {
  __shared__ unsigned short lds[2 * 12288];   // 48KB: 2 x (A[128][32] + B[256][32])
  const int by = blockIdx.y;
  if (by >= tp[NE]) return;
  int e = 0;
#pragma unroll
  for (int k = 1; k < NE; k++) if (by >= tp[k]) e = k;
  const int ne = counts[e], rs = row_start[e];
  const int m0 = (by - tp[e]) * 128;
  const int n0 = blockIdx.x * 256;            // interleaved col space [0,4096)

  const int tid = threadIdx.x;
  const int wave = tid >> 6, lane = tid & 63;
  const int lr = lane & 15, lk = lane >> 4;
  const int wm = (wave & 1) * 64, wn = (wave >> 1) * 128;

  // staging: instr covers rows base+ (lane>>2), slot lane&3; swizzle slot' = slot ^ ((row>>1)&3)
  const int srow = lane >> 2;                               // 0..15 (row mod 16)
  const int scs = ((lane & 3) ^ ((srow >> 1) & 3)) * 8;     // inverse-swizzled source col
  const unsigned short* asrc[2];
  const unsigned short* bsrc[4];
#pragma unroll
  for (int i = 0; i < 2; i++) {
    int sr = (wave * 2 + i) * 16 + srow;                    // 0..127
    int rr = m0 + sr; if (rr >= ne) rr = m0;
    int tok = list[rs + rr] >> 1;
    asrc[i] = Xb + (size_t)tok * DIM + scs;
  }
#pragma unroll
  for (int i = 0; i < 4; i++) {
    int sr = (wave * 4 + i) * 16 + srow;                    // 0..255
    bsrc[i] = W13t + ((size_t)e * 2 * HID + n0 + sr) * DIM + scs;
  }

  f32x4 acc[4][8];
  const f32x4 zero = {0.f, 0.f, 0.f, 0.f};
#pragma unroll
  for (int m = 0; m < 4; m++)
#pragma unroll
    for (int n = 0; n < 8; n++) acc[m][n] = zero;

  auto STAGE = [&](int t, int buf) {
    unsigned short* p = lds + buf * 12288;
    const int ko = t * 32;
#pragma unroll
    for (int i = 0; i < 2; i++) gload16(asrc[i] + ko, p + (wave * 2 + i) * 512);
#pragma unroll
    for (int i = 0; i < 4; i++) gload16(bsrc[i] + ko, p + 4096 + (wave * 4 + i) * 512);
  };
  const int slot = (lk ^ ((lr >> 1) & 3)) * 8;
  auto COMPUTE = [&](int buf) {
    const unsigned short* Ab = lds + buf * 12288;
    const unsigned short* Bb = Ab + 4096;
    bf16x8 a[4], b[8];
#pragma unroll
    for (int m = 0; m < 4; m++)
      a[m] = *(const bf16x8*)&Ab[(wm + m * 16 + lr) * 32 + slot];
#pragma unroll
    for (int n = 0; n < 8; n++)
      b[n] = *(const bf16x8*)&Bb[(wn + n * 16 + lr) * 32 + slot];
    __builtin_amdgcn_s_setprio(1);
#pragma unroll
    for (int m = 0; m < 4; m++)
#pragma unroll
      for (int n = 0; n < 8; n++)
        acc[m][n] = __builtin_amdgcn_mfma_f32_16x16x32_bf16(a[m], b[n], acc[m][n], 0, 0, 0);
    __builtin_amdgcn_s_setprio(0);
  };

  const int NT = DIM / 32;   // 32, even
  STAGE(0, 0); VMC0; BARR;
  for (int t = 0; t < NT; t += 2) {
    if (t + 1 < NT) STAGE(t + 1, 1);
    COMPUTE(0); VMC0; BARR;
    if (t + 2 < NT) STAGE(t + 2, 0);
    COMPUTE(1); VMC0; BARR;
  }

  // SwiGLU epilogue: pairs (2g,2g+1) = (h1,h3); h = ((n0+wn)>>1) + g*16 + lr
  const int hbase = (n0 + wn) >> 1;
#pragma unroll
  for (int g = 0; g < 4; g++) {
    int h = hbase + g * 16 + lr;
    float b1v = b1[e * HID + h];
    float b3v = b3[e * HID + h];
#pragma unroll
    for (int m = 0; m < 4; m++) {
#pragma unroll
      for (int j = 0; j < 4; j++) {
        int rr = m0 + wm + m * 16 + lk * 4 + j;
        if (rr < ne) {
          float h1 = acc[m][2 * g][j] + b1v;
          float h3 = acc[m][2 * g + 1][j] + b3v;
          float v = h1 * h3;
          h_buf[(size_t)(rs + rr) * HID + h] = f2bf(v / (1.f + expf(-v)));
        }
      }
    }
  }
}

// ============ stage B: tile 128x256, 4 waves (per-wave 64x128), BK=32, dbuf ============
__global__ __launch_bounds__(256, 3) void ffn_b_kernel(
    const unsigned short* __restrict__ h_buf,
    const unsigned short* __restrict__ W2t,
    const float* __restrict__ b2,
    const int* __restrict__ counts, const int* __restrict__ row_start,
    const int* __restrict__ tp, const int* __restrict__ list,
    const float* __restrict__ topk_w, float* __restrict__ o_buf) {
  __shared__ unsigned short lds[2 * 12288];
  const int by = blockIdx.y;
  if (by >= tp[NE]) return;
  int e = 0;
#pragma unroll
  for (int k = 1; k < NE; k++) if (by >= tp[k]) e = k;
  const int ne = counts[e], rs = row_start[e];
  const int m0 = (by - tp[e]) * 128;
  const int n0 = blockIdx.x * 256;

  const int tid = threadIdx.x;
  const int wave = tid >> 6, lane = tid & 63;
  const int lr = lane & 15, lk = lane >> 4;
  const int wm = (wave & 1) * 64, wn = (wave >> 1) * 128;

  const int srow = lane >> 2;
  const int scs = ((lane & 3) ^ ((srow >> 1) & 3)) * 8;
  const unsigned short* asrc[2];
  const unsigned short* bsrc[4];
#pragma unroll
  for (int i = 0; i < 2; i++) {
    int sr = (wave * 2 + i) * 16 + srow;
    asrc[i] = h_buf + (size_t)(rs + m0 + sr) * HID + scs;   // padded rows, in-bounds
  }
#pragma unroll
  for (int i = 0; i < 4; i++) {
    int sr = (wave * 4 + i) * 16 + srow;
    bsrc[i] = W2t + ((size_t)e * OUTD + n0 + sr) * HID + scs;
  }

  f32x4 acc[4][8];
  const f32x4 zero = {0.f, 0.f, 0.f, 0.f};
#pragma unroll
  for (int m = 0; m < 4; m++)
#pragma unroll
    for (int n = 0; n < 8; n++) acc[m][n] = zero;

  auto STAGE = [&](int t, int buf) {
    unsigned short* p = lds + buf * 12288;
    const int ko = t * 32;
#pragma unroll
    for (int i = 0; i < 2; i++) gload16(asrc[i] + ko, p + (wave * 2 + i) * 512);
#pragma unroll
    for (int i = 0; i < 4; i++) gload16(bsrc[i] + ko, p + 4096 + (wave * 4 + i) * 512);
  };
  const int slot = (lk ^ ((lr >> 1) & 3)) * 8;
  auto COMPUTE = [&](int buf) {
    const unsigned short* Ab = lds + buf * 12288;
    const unsigned short* Bb = Ab + 4096;
    bf16x8 a[4], b[8];
#pragma unroll
    for (int m = 0; m < 4; m++)
      a[m] = *(const bf16x8*)&Ab[(wm + m * 16 + lr) * 32 + slot];
#pragma unroll
    for (int n = 0; n < 8; n++)
      b[n] = *(const bf16x8*)&Bb[(wn + n * 16 + lr) * 32 + slot];
    __builtin_amdgcn_s_setprio(1);
#pragma unroll
    for (int m = 0; m < 4; m++)
#pragma unroll
      for (int n = 0; n < 8; n++)
        acc[m][n] = __builtin_amdgcn_mfma_f32_16x16x32_bf16(a[m], b[n], acc[m][n], 0, 0, 0);
    __builtin_amdgcn_s_setprio(0);
  };

  const int NT = HID / 32;   // 64, even
  STAGE(0, 0); VMC0; BARR;
  for (int t = 0; t < NT; t += 2) {
    if (t + 1 < NT) STAGE(t + 1, 1);
    COMPUTE(0); VMC0; BARR;
    if (t + 2 < NT) STAGE(t + 2, 0);
    COMPUTE(1); VMC0; BARR;
  }

#pragma unroll
  for (int n = 0; n < 8; n++) {
    int col = n0 + wn + n * 16 + lr;
    float b2v = b2[e * OUTD + col];
#pragma unroll
    for (int m = 0; m < 4; m++) {
#pragma unroll
      for (int j = 0; j < 4; j++) {
        int rr = m0 + wm + m * 16 + lk * 4 + j;
        if (rr < ne) {
          int entry = list[rs + rr];
          float w = topk_w[entry];
          o_buf[(size_t)entry * OUTD + col] = w * (acc[m][n][j] + b2v);
        }
      }
    }
  }
}

// ---------------- final: out = (o0 + o1) @ Wf + bf ----------------
__global__ __launch_bounds__(256) void final_kernel(
    const float* __restrict__ o_buf, const unsigned short* __restrict__ Wft,
    const float* __restrict__ bfv, float* __restrict__ out) {
  const int m0 = blockIdx.y * 128, n0 = blockIdx.x * 128;

  __shared__ unsigned short As[128 * 64];
  __shared__ unsigned short Bs[128 * 64];

  const int tid = threadIdx.x;
  const int wave = tid >> 6, lane = tid & 63;
  const int lrow = lane >> 3;
  const int lcol = (lane & 7) * 8;

  const unsigned short* bsrc[4];
#pragma unroll
  for (int i = 0; i < 4; i++) {
    int sr = (wave * 4 + i) * 8 + lrow;
    bsrc[i] = Wft + (size_t)(n0 + sr) * DIM + lcol;
  }

  const int wm = (wave >> 1) * 64, wn = (wave & 1) * 64;
  const int lr = lane & 15, lk = lane >> 4;

  f32x4 acc[4][4];
  const f32x4 zero = {0.f, 0.f, 0.f, 0.f};
#pragma unroll
  for (int m = 0; m < 4; m++)
#pragma unroll
    for (int n = 0; n < 4; n++) acc[m][n] = zero;

  for (int k0 = 0; k0 < DIM; k0 += 64) {
#pragma unroll
    for (int g = 0; g < 8; g++) {
      int idx = g * 256 + tid;
      int r = idx >> 4;
      int c4 = (idx & 15) * 4;
      const float4 v0 = *(const float4*)&o_buf[(size_t)(m0 + r) * 2 * OUTD + k0 + c4];
      const float4 v1 = *(const float4*)&o_buf[(size_t)(m0 + r) * 2 * OUTD + OUTD + k0 + c4];
      ushort4 u;
      u.x = f2bf(v0.x + v1.x); u.y = f2bf(v0.y + v1.y);
      u.z = f2bf(v0.z + v1.z); u.w = f2bf(v0.w + v1.w);
      *(ushort4*)&As[r * 64 + c4] = u;
    }
#pragma unroll
    for (int i = 0; i < 4; i++) gload16(bsrc[i] + k0, &Bs[(wave * 4 + i) * 512]);
    __syncthreads();
#pragma unroll
    for (int kk = 0; kk < 2; kk++) {
      bf16x8 a[4], b[4];
#pragma unroll
      for (int m = 0; m < 4; m++)
        a[m] = *(const bf16x8*)&As[(wm + m * 16 + lr) * 64 + kk * 32 + lk * 8];
#pragma unroll
      for (int n = 0; n < 4; n++)
        b[n] = *(const bf16x8*)&Bs[(wn + n * 16 + lr) * 64 + kk * 32 + lk * 8];
#pragma unroll
      for (int m = 0; m < 4; m++)
#pragma unroll
        for (int n = 0; n < 4; n++)
          acc[m][n] = __builtin_amdgcn_mfma_f32_16x16x32_bf16(a[m], b[n], acc[m][n], 0, 0, 0);
    }
    __syncthreads();
  }

#pragma unroll
  for (int n = 0; n < 4; n++) {
    int col = n0 + wn + n * 16 + lr;
    float bv = bfv[col];
#pragma unroll
    for (int m = 0; m < 4; m++) {
#pragma unroll
      for (int j = 0; j < 4; j++) {
        int r = m0 + wm + m * 16 + lk * 4 + j;
        out[(size_t)r * OUTD + col] = acc[m][n][j] + bv;
      }
    }
  }
}

extern "C" void kernel_launch(void* const* d_in, const int* in_sizes, int n_in,
                              void* d_out, int out_size, void* d_ws, size_t ws_size,
                              hipStream_t stream) {
  const float* X   = (const float*)d_in[0];
  const float* W1  = (const float*)d_in[1];
  const float* b1  = (const float*)d_in[2];
  const float* W3  = (const float*)d_in[3];
  const float* b3  = (const float*)d_in[4];
  const float* W2  = (const float*)d_in[5];
  const float* b2  = (const float*)d_in[6];
  const float* Wg  = (const float*)d_in[7];
  const float* bg  = (const float*)d_in[8];
  const float* Wf  = (const float*)d_in[9];
  const float* bfv = (const float*)d_in[10];
  float* out = (float*)d_out;

  char* p = (char*)d_ws;
  auto alloc = [&](size_t bytes) { char* r = p; p += (bytes + 255) & ~(size_t)255; return r; };
  unsigned short* Xb   = (unsigned short*)alloc((size_t)NTOK * DIM * 2);
  unsigned short* W13t = (unsigned short*)alloc((size_t)NE * 2 * HID * DIM * 2);
  unsigned short* W2t  = (unsigned short*)alloc((size_t)NE * OUTD * HID * 2);
  unsigned short* Wft  = (unsigned short*)alloc((size_t)OUTD * DIM * 2);
  unsigned short* hbuf = (unsigned short*)alloc((size_t)(NTOK * 2 + 256) * HID * 2);
  float* o_buf         = (float*)alloc((size_t)NTOK * 2 * OUTD * 4);
  int* topk_pack       = (int*)alloc(NTOK * 4);
  float* topk_w        = (float*)alloc(NTOK * 2 * 4);
  int* counts          = (int*)alloc(NE * 4);
  int* row_start       = (int*)alloc(NE * 4);
  int* tp              = (int*)alloc((NE + 1) * 4);
  int* blkcnt          = (int*)alloc(128 * NE * 4);
  int* list            = (int*)alloc(NTOK * 2 * 4);

  gating_kernel<<<128, 256, 0, stream>>>(X, Wg, bg, Xb, topk_pack, topk_w, blkcnt);
  tcast_i_kernel<<<dim3(HID / 32, DIM / 32, 16), 256, 0, stream>>>(W1, W3, W13t);
  tcast_kernel<<<dim3(OUTD / 32, HID / 32, NE), 256, 0, stream>>>(W2, W2t, HID, OUTD);
  tcast_kernel<<<dim3(OUTD / 32, DIM / 32, 1), 256, 0, stream>>>(Wf, Wft, DIM, OUTD);

  scatter_kernel<<<128, 64, 0, stream>>>(blkcnt, topk_pack, counts, row_start, tp, list);

  // tile-compact grids, BM=128: max sum ceil(ne/128) = 64+7 = 71 -> 72
  ffn_a_kernel<<<dim3(2 * HID / 256, 72), 256, 0, stream>>>(
      Xb, W13t, b1, b3, counts, row_start, tp, list, hbuf);
  ffn_b_kernel<<<dim3(OUTD / 256, 72), 256, 0, stream>>>(
      hbuf, W2t, b2, counts, row_start, tp, list, topk_w, o_buf);
  final_kernel<<<dim3(OUTD / 128, NTOK / 128), 256, 0, stream>>>(o_buf, Wft, bfv, out);
}

// Round 9
// 312.677 us; speedup vs baseline: 4.2390x; 4.2390x over previous
//
#include <hip/hip_runtime.h>

#define DIM  1024
#define HID  2048
#define OUTD 1024
#define NE   8
#define NTOK 4096

using bf16x8 = __attribute__((ext_vector_type(8))) short;
using f32x4  = __attribute__((ext_vector_type(4))) float;

__device__ __forceinline__ unsigned short f2bf(float f) {
  unsigned int u = __builtin_bit_cast(unsigned int, f);
  u += 0x7fff + ((u >> 16) & 1);   // round-to-nearest-even
  return (unsigned short)(u >> 16);
}
__device__ __forceinline__ float b2f(unsigned short u) {
  unsigned int v = (unsigned int)u << 16;
  return __builtin_bit_cast(float, v);
}

__device__ __forceinline__ void gload16(const void* g, void* l) {
  __builtin_amdgcn_global_load_lds(
      (const __attribute__((address_space(1))) void*)g,
      (__attribute__((address_space(3))) void*)l, 16, 0, 0);
}

#define BARR __builtin_amdgcn_s_barrier()
#define VMC(n) asm volatile("s_waitcnt vmcnt(" #n ")" ::: "memory")

// ---------------- transpose + cast: in [R][C] fp32 -> out [C][R] bf16 ----------------
__global__ void tcast_kernel(const float* __restrict__ in,
                             unsigned short* __restrict__ out, int R, int C) {
  __shared__ float tile[32][33];
  size_t zo = (size_t)blockIdx.z * R * C;
  int c0 = blockIdx.x * 32, r0 = blockIdx.y * 32;
  int tx = threadIdx.x & 31, ty = threadIdx.x >> 5;
#pragma unroll
  for (int j = 0; j < 4; j++) {
    int r = ty + j * 8;
    tile[r][tx] = in[zo + (size_t)(r0 + r) * C + c0 + tx];
  }
  __syncthreads();
  int c = threadIdx.x >> 3, q = threadIdx.x & 7;
  ushort4 u;
  u.x = f2bf(tile[q * 4 + 0][c]); u.y = f2bf(tile[q * 4 + 1][c]);
  u.z = f2bf(tile[q * 4 + 2][c]); u.w = f2bf(tile[q * 4 + 3][c]);
  *(ushort4*)&out[zo + (size_t)(c0 + c) * R + r0 + q * 4] = u;
}

// ---- transpose+cast W1/W3 [NE][DIM][HID] -> interleaved W13t [NE][2*HID][DIM]
__global__ void tcast_i_kernel(const float* __restrict__ W1,
                               const float* __restrict__ W3,
                               unsigned short* __restrict__ out) {
  __shared__ float tile[32][33];
  int z = blockIdx.z, e = z & 7, s = z >> 3;
  const float* inp = (s ? W3 : W1) + (size_t)e * DIM * HID;
  unsigned short* op = out + (size_t)e * 2 * HID * DIM;
  int c0 = blockIdx.x * 32, r0 = blockIdx.y * 32;
  int tx = threadIdx.x & 31, ty = threadIdx.x >> 5;
#pragma unroll
  for (int j = 0; j < 4; j++) {
    int r = ty + j * 8;
    tile[r][tx] = inp[(size_t)(r0 + r) * HID + c0 + tx];
  }
  __syncthreads();
  int c = threadIdx.x >> 3, q = threadIdx.x & 7;
  int h = c0 + c;
  int orow = 32 * (h >> 4) + 16 * s + (h & 15);
  ushort4 u;
  u.x = f2bf(tile[q * 4 + 0][c]); u.y = f2bf(tile[q * 4 + 1][c]);
  u.z = f2bf(tile[q * 4 + 2][c]); u.w = f2bf(tile[q * 4 + 3][c]);
  *(ushort4*)&op[(size_t)orow * DIM + r0 + q * 4] = u;
}

// ---------------- gating + fused X cast + per-block histogram ----------------
__global__ __launch_bounds__(256) void gating_kernel(
    const float* __restrict__ X, const float* __restrict__ Wg,
    const float* __restrict__ bg, unsigned short* __restrict__ Xb,
    int* __restrict__ topk_pack, float* __restrict__ topk_w,
    int* __restrict__ blkcnt) {
  __shared__ float wgs[NE][DIM];
  __shared__ int hist[NE];
  const int tid = threadIdx.x;
  for (int d = tid; d < DIM; d += 256) {
#pragma unroll
    for (int e = 0; e < NE; e++) wgs[e][d] = Wg[d * NE + e];
  }
  if (tid < NE) hist[tid] = 0;
  __syncthreads();
  const int wave = tid >> 6, lane = tid & 63;
  for (int tk = wave; tk < 32; tk += 4) {
    const int t = blockIdx.x * 32 + tk;
    const float* xr = X + (size_t)t * DIM;
    {
      const float4* xp = (const float4*)(xr + lane * 16);
      float4 v0 = xp[0], v1 = xp[1], v2 = xp[2], v3 = xp[3];
      uint4 w0, w1;
      w0.x = f2bf(v0.x) | ((unsigned)f2bf(v0.y) << 16);
      w0.y = f2bf(v0.z) | ((unsigned)f2bf(v0.w) << 16);
      w0.z = f2bf(v1.x) | ((unsigned)f2bf(v1.y) << 16);
      w0.w = f2bf(v1.z) | ((unsigned)f2bf(v1.w) << 16);
      w1.x = f2bf(v2.x) | ((unsigned)f2bf(v2.y) << 16);
      w1.y = f2bf(v2.z) | ((unsigned)f2bf(v2.w) << 16);
      w1.z = f2bf(v3.x) | ((unsigned)f2bf(v3.y) << 16);
      w1.w = f2bf(v3.z) | ((unsigned)f2bf(v3.w) << 16);
      uint4* op2 = (uint4*)(Xb + (size_t)t * DIM + lane * 16);
      op2[0] = w0; op2[1] = w1;
    }
    float acc[NE];
#pragma unroll
    for (int e = 0; e < NE; e++) acc[e] = 0.f;
#pragma unroll
    for (int j = 0; j < 16; j++) {
      float xv = xr[lane + j * 64];
#pragma unroll
      for (int e = 0; e < NE; e++) acc[e] += xv * wgs[e][lane + j * 64];
    }
#pragma unroll
    for (int e = 0; e < NE; e++) {
#pragma unroll
      for (int off = 32; off > 0; off >>= 1) acc[e] += __shfl_xor(acc[e], off, 64);
    }
    if (lane == 0) {
      float p[NE];
      float mx = -1e30f;
#pragma unroll
      for (int e = 0; e < NE; e++) { p[e] = acc[e] + bg[e]; mx = fmaxf(mx, p[e]); }
      float sum = 0.f;
#pragma unroll
      for (int e = 0; e < NE; e++) { p[e] = expf(p[e] - mx); sum += p[e]; }
      float inv = 1.f / sum;
#pragma unroll
      for (int e = 0; e < NE; e++) p[e] *= inv;
      int i1 = 0; float v1 = p[0];
#pragma unroll
      for (int e = 1; e < NE; e++) if (p[e] >= v1) { v1 = p[e]; i1 = e; }
      int i2 = (i1 == 0) ? 1 : 0; float v2 = p[i2];
#pragma unroll
      for (int e = 0; e < NE; e++) {
        if (e == i1) continue;
        if (p[e] >= v2 && e != i2) { v2 = p[e]; i2 = e; }
      }
      topk_pack[t] = i1 | (i2 << 4);
      topk_w[t * 2 + 0] = v1; topk_w[t * 2 + 1] = v2;
      atomicAdd(&hist[i1], 1); atomicAdd(&hist[i2], 1);
    }
  }
  __syncthreads();
  if (tid < NE) blkcnt[blockIdx.x * NE + tid] = hist[tid];
}

// ------- scatter with integrated prefix; emits tpA (BM=256) and tpB (BM=128) -------
__global__ void scatter_kernel(const int* __restrict__ blkcnt,
                               const int* __restrict__ topk_pack,
                               int* __restrict__ counts, int* __restrict__ row_start,
                               int* __restrict__ tpA, int* __restrict__ tpB,
                               int* __restrict__ list) {
  __shared__ int lofs[NE];
  const int lane = threadIdx.x;   // 64
  const int myb = blockIdx.x;     // 128
  int s = 0, tA = 0, tB = 0;
#pragma unroll
  for (int e = 0; e < NE; e++) {
    int c0 = blkcnt[lane * NE + e], c1 = blkcnt[(lane + 64) * NE + e];
    int tote = c0 + c1;
    int pre = (lane < myb ? c0 : 0) + (lane + 64 < myb ? c1 : 0);
#pragma unroll
    for (int off = 32; off > 0; off >>= 1) {
      tote += __shfl_xor(tote, off, 64);
      pre  += __shfl_xor(pre,  off, 64);
    }
    if (lane == 0) lofs[e] = s + pre;
    if (myb == 0 && lane == 0) {
      counts[e] = tote; row_start[e] = s; tpA[e] = tA; tpB[e] = tB;
    }
    s += tote; tA += (tote + 255) >> 8; tB += (tote + 127) >> 7;
  }
  if (myb == 0 && lane == 0) { tpA[NE] = tA; tpB[NE] = tB; }
  __syncthreads();
  if (lane < 32) {
    int tok = myb * 32 + lane;
    int pk = topk_pack[tok];
    int e1 = pk & 15, e2 = (pk >> 4) & 15;
    int p1 = atomicAdd(&lofs[e1], 1); list[p1] = tok << 1;
    int p2 = atomicAdd(&lofs[e2], 1); list[p2] = (tok << 1) | 1;
  }
}

// ========== stage A: 256x256, BK=64, 8-phase counted-vmcnt + T2 swizzle + T5 ==========
// LDS per dbuf: Ak0[256][32] Ak1[256][32] Bk0[256][32] Bk1[256][32]; dbuf stride 32768.
// 64B rows; LDS slot q of row r holds global 16B-col (q ^ ((r>>1)&3))  [conflict-free]
#define FA_NT 16
#define FA_IT 8
__global__ __launch_bounds__(512, 2) void ffn_a_kernel(
    const unsigned short* __restrict__ Xb,
    const unsigned short* __restrict__ W13t,
    const float* __restrict__ b1, const float* __restrict__ b3,
    const int* __restrict__ counts, const int* __restrict__ row_start,
    const int* __restrict__ tpA,
    const int* __restrict__ list, unsigned short* __restrict__ h_buf) {
  extern __shared__ unsigned short lds[];
  const int by = blockIdx.y;
  if (by >= tpA[NE]) return;
  int e = 0;
#pragma unroll
  for (int k = 1; k < NE; k++) if (by >= tpA[k]) e = k;
  const int ne = counts[e];
  const int rs = row_start[e];
  const int m0 = (by - tpA[e]) * 256;
  const int n0 = blockIdx.x * 256;

  const int tid = threadIdx.x;
  const int wave = tid >> 6, lane = tid & 63;
  const int lr = lane & 15, lk = lane >> 4;
  const int WM = (wave >> 2) * 128, WN = (wave & 3) * 64;

  // staging: row r = c*128 + wave*16 + (lane>>2); swizzled 16B slot
  const int srow = wave * 16 + (lane >> 2);
  const int scs = ((lane & 3) ^ ((srow >> 1) & 3)) * 8;
  const unsigned short* aptr[2];
  const unsigned short* bptr[2];
#pragma unroll
  for (int c = 0; c < 2; c++) {
    int r = c * 128 + srow;
    int rr = m0 + r; if (rr >= ne) rr = m0;
    int tok = list[rs + rr] >> 1;
    aptr[c] = Xb + (size_t)tok * DIM + scs;
    bptr[c] = W13t + ((size_t)e * 2 * HID + n0 + r) * DIM + scs;
  }

  f32x4 acc[8][4];
  const f32x4 zero = {0.f, 0.f, 0.f, 0.f};
#pragma unroll
  for (int m = 0; m < 8; m++)
#pragma unroll
    for (int n = 0; n < 4; n++) acc[m][n] = zero;

  bf16x8 aa[4], bb[4];
  const int rsl = (lk ^ ((lr >> 1) & 3)) * 8;   // swizzled read slot (shorts)

  auto STG = [&](int tile, int isB, int kk) {
    if (tile >= FA_NT) return;
    unsigned short* hb = lds + (tile & 1) * 32768 + isB * 16384 + kk * 8192 + wave * 512;
    const int ko = tile * 64 + kk * 32;
    if (!isB) { gload16(aptr[0] + ko, hb); gload16(aptr[1] + ko, hb + 4096); }
    else      { gload16(bptr[0] + ko, hb); gload16(bptr[1] + ko, hb + 4096); }
  };
  auto DSB = [&](int d, int kk) {
#pragma unroll
    for (int n = 0; n < 4; n++) {
      int row = WN + n * 16 + lr;
      bb[n] = *(const bf16x8*)&lds[d * 32768 + 16384 + kk * 8192 + row * 32 + rsl];
    }
  };
  auto DSA = [&](int d, int kk, int mh) {
#pragma unroll
    for (int mi = 0; mi < 4; mi++) {
      int row = WM + (mh * 4 + mi) * 16 + lr;
      aa[mi] = *(const bf16x8*)&lds[d * 32768 + kk * 8192 + row * 32 + rsl];
    }
  };
  auto MM = [&](int mh) {
    __builtin_amdgcn_s_setprio(1);
#pragma unroll
    for (int mi = 0; mi < 4; mi++)
#pragma unroll
      for (int n = 0; n < 4; n++)
        acc[mh * 4 + mi][n] =
            __builtin_amdgcn_mfma_f32_16x16x32_bf16(aa[mi], bb[n], acc[mh * 4 + mi][n], 0, 0, 0);
    __builtin_amdgcn_s_setprio(0);
  };

  // prologue: t0 fully + 3 halves of t1; vmcnt(6) -> t0's 8 loads landed
  STG(0, 0, 0); STG(0, 1, 0); STG(0, 0, 1); STG(0, 1, 1);
  STG(1, 1, 0); STG(1, 0, 0); STG(1, 1, 1);
  VMC(6); BARR;

  for (int i = 0; i < FA_IT; ++i) {
    const int t1 = 2 * i + 1, t2 = 2 * i + 2, t3 = 2 * i + 3;
    DSB(0, 0); DSA(0, 0, 0); STG(t1, 0, 1); BARR; MM(0); BARR;
    DSA(0, 0, 1); STG(t2, 1, 0); BARR; MM(1); BARR;
    DSB(0, 1); DSA(0, 1, 0); STG(t2, 0, 0); BARR; MM(0); BARR;
    DSA(0, 1, 1); STG(t2, 1, 1);
    if (i < FA_IT - 1) { VMC(6); } else { VMC(0); }
    BARR; MM(1); BARR;
    DSB(1, 0); DSA(1, 0, 0); STG(t2, 0, 1); BARR; MM(0); BARR;
    DSA(1, 0, 1); STG(t3, 1, 0); BARR; MM(1); BARR;
    DSB(1, 1); DSA(1, 1, 0); STG(t3, 0, 0); BARR; MM(0); BARR;
    DSA(1, 1, 1); STG(t3, 1, 1);
    if (i < FA_IT - 1) { VMC(6); }
    BARR; MM(1); BARR;
  }

  // SwiGLU epilogue: frag pair (2g,2g+1) = (h1,h3); h = ((n0+WN)>>1) + g*16 + lr
  const int hbase = (n0 + WN) >> 1;
#pragma unroll
  for (int g = 0; g < 2; g++) {
    int h = hbase + g * 16 + lr;
    float b1v = b1[e * HID + h];
    float b3v = b3[e * HID + h];
#pragma unroll
    for (int m = 0; m < 8; m++) {
#pragma unroll
      for (int j = 0; j < 4; j++) {
        int rr = m0 + WM + m * 16 + lk * 4 + j;
        if (rr < ne) {
          float h1 = acc[m][2 * g][j] + b1v;
          float h3 = acc[m][2 * g + 1][j] + b3v;
          float v = h1 * h3;
          h_buf[(size_t)(rs + rr) * HID + h] = f2bf(v / (1.f + expf(-v)));
        }
      }
    }
  }
}

// ============ stage B: 128x128, BK=64, m97 single-buffer (R6-proven), bf16 out ============
__global__ __launch_bounds__(256, 3) void ffn_b_kernel(
    const unsigned short* __restrict__ h_buf,
    const unsigned short* __restrict__ W2t,
    const float* __restrict__ b2,
    const int* __restrict__ counts, const int* __restrict__ row_start,
    const int* __restrict__ tpB, const int* __restrict__ list,
    const float* __restrict__ topk_w, unsigned short* __restrict__ ob) {
  __shared__ unsigned short As[128 * 64];
  __shared__ unsigned short Bs[128 * 64];
  const int by = blockIdx.y;
  if (by >= tpB[NE]) return;
  int e = 0;
#pragma unroll
  for (int k = 1; k < NE; k++) if (by >= tpB[k]) e = k;
  const int ne = counts[e], rs = row_start[e];
  const int m0 = (by - tpB[e]) * 128;
  const int n0 = blockIdx.x * 128;

  const int tid = threadIdx.x;
  const int wave = tid >> 6, lane = tid & 63;
  const int lr = lane & 15, lk = lane >> 4;
  const int wm = (wave >> 1) * 64, wn = (wave & 1) * 64;

  const int scs = ((lane & 7) ^ (lane >> 3)) * 8;
  const unsigned short* asrc[4];
  const unsigned short* bsrc[4];
#pragma unroll
  for (int i = 0; i < 4; i++) {
    int sr = (wave * 4 + i) * 8 + (lane >> 3);
    asrc[i] = h_buf + (size_t)(rs + m0 + sr) * HID + scs;   // padded rows, in-bounds
    bsrc[i] = W2t + ((size_t)e * OUTD + n0 + sr) * HID + scs;
  }

  f32x4 acc[4][4];
  const f32x4 zero = {0.f, 0.f, 0.f, 0.f};
#pragma unroll
  for (int m = 0; m < 4; m++)
#pragma unroll
    for (int n = 0; n < 4; n++) acc[m][n] = zero;

  const int sx = lr & 7;

  for (int k0 = 0; k0 < HID; k0 += 64) {
#pragma unroll
    for (int i = 0; i < 4; i++) {
      gload16(asrc[i] + k0, &As[(wave * 4 + i) * 512]);
      gload16(bsrc[i] + k0, &Bs[(wave * 4 + i) * 512]);
    }
    __syncthreads();
#pragma unroll
    for (int kk = 0; kk < 2; kk++) {
      const int sl = ((kk * 4 + lk) ^ sx) * 8;
      bf16x8 a[4], b[4];
#pragma unroll
      for (int m = 0; m < 4; m++)
        a[m] = *(const bf16x8*)&As[(wm + m * 16 + lr) * 64 + sl];
#pragma unroll
      for (int n = 0; n < 4; n++)
        b[n] = *(const bf16x8*)&Bs[(wn + n * 16 + lr) * 64 + sl];
#pragma unroll
      for (int m = 0; m < 4; m++)
#pragma unroll
        for (int n = 0; n < 4; n++)
          acc[m][n] = __builtin_amdgcn_mfma_f32_16x16x32_bf16(a[m], b[n], acc[m][n], 0, 0, 0);
    }
    __syncthreads();
  }

#pragma unroll
  for (int n = 0; n < 4; n++) {
    int col = n0 + wn + n * 16 + lr;
    float b2v = b2[e * OUTD + col];
#pragma unroll
    for (int m = 0; m < 4; m++) {
#pragma unroll
      for (int j = 0; j < 4; j++) {
        int rr = m0 + wm + m * 16 + lk * 4 + j;
        if (rr < ne) {
          int entry = list[rs + rr];
          float w = topk_w[entry];
          ob[(size_t)entry * OUTD + col] = f2bf(w * (acc[m][n][j] + b2v));
        }
      }
    }
  }
}

// ---------------- final: out = (ob0 + ob1) @ Wf + bf ; XCD-grouped m-bands ----------------
__global__ __launch_bounds__(256) void final_kernel(
    const unsigned short* __restrict__ ob, const unsigned short* __restrict__ Wft,
    const float* __restrict__ bfv, float* __restrict__ out) {
  const int bid = blockIdx.x;
  const int n0 = (bid >> 5) * 128;
  const int m0 = ((bid & 7) + 8 * ((bid >> 3) & 3)) * 128;

  __shared__ unsigned short As[128 * 64];
  __shared__ unsigned short Bs[128 * 64];

  const int tid = threadIdx.x;
  const int wave = tid >> 6, lane = tid & 63;
  const int lrow = lane >> 3;
  const int lcol = (lane & 7) * 8;

  const unsigned short* bsrc[4];
#pragma unroll
  for (int i = 0; i < 4; i++) {
    int sr = (wave * 4 + i) * 8 + lrow;
    bsrc[i] = Wft + (size_t)(n0 + sr) * DIM + lcol;
  }

  const int wm = (wave >> 1) * 64, wn = (wave & 1) * 64;
  const int lr = lane & 15, lk = lane >> 4;

  f32x4 acc[4][4];
  const f32x4 zero = {0.f, 0.f, 0.f, 0.f};
#pragma unroll
  for (int m = 0; m < 4; m++)
#pragma unroll
    for (int n = 0; n < 4; n++) acc[m][n] = zero;

  for (int k0 = 0; k0 < DIM; k0 += 64) {
#pragma unroll
    for (int g = 0; g < 8; g++) {
      int idx = g * 256 + tid;
      int r = idx >> 4;
      int c4 = (idx & 15) * 4;
      ushort4 a0 = *(const ushort4*)&ob[((size_t)(m0 + r) * 2) * OUTD + k0 + c4];
      ushort4 a1 = *(const ushort4*)&ob[((size_t)(m0 + r) * 2 + 1) * OUTD + k0 + c4];
      ushort4 u;
      u.x = f2bf(b2f(a0.x) + b2f(a1.x)); u.y = f2bf(b2f(a0.y) + b2f(a1.y));
      u.z = f2bf(b2f(a0.z) + b2f(a1.z)); u.w = f2bf(b2f(a0.w) + b2f(a1.w));
      *(ushort4*)&As[r * 64 + c4] = u;
    }
#pragma unroll
    for (int i = 0; i < 4; i++) gload16(bsrc[i] + k0, &Bs[(wave * 4 + i) * 512]);
    __syncthreads();
#pragma unroll
    for (int kk = 0; kk < 2; kk++) {
      bf16x8 a[4], b[4];
#pragma unroll
      for (int m = 0; m < 4; m++)
        a[m] = *(const bf16x8*)&As[(wm + m * 16 + lr) * 64 + kk * 32 + lk * 8];
#pragma unroll
      for (int n = 0; n < 4; n++)
        b[n] = *(const bf16x8*)&Bs[(wn + n * 16 + lr) * 64 + kk * 32 + lk * 8];
#pragma unroll
      for (int m = 0; m < 4; m++)
#pragma unroll
        for (int n = 0; n < 4; n++)
          acc[m][n] = __builtin_amdgcn_mfma_f32_16x16x32_bf16(a[m], b[n], acc[m][n], 0, 0, 0);
    }
    __syncthreads();
  }

#pragma unroll
  for (int n = 0; n < 4; n++) {
    int col = n0 + wn + n * 16 + lr;
    float bv = bfv[col];
#pragma unroll
    for (int m = 0; m < 4; m++) {
#pragma unroll
      for (int j = 0; j < 4; j++) {
        int r = m0 + wm + m * 16 + lk * 4 + j;
        out[(size_t)r * OUTD + col] = acc[m][n][j] + bv;
      }
    }
  }
}

extern "C" void kernel_launch(void* const* d_in, const int* in_sizes, int n_in,
                              void* d_out, int out_size, void* d_ws, size_t ws_size,
                              hipStream_t stream) {
  const float* X   = (const float*)d_in[0];
  const float* W1  = (const float*)d_in[1];
  const float* b1  = (const float*)d_in[2];
  const float* W3  = (const float*)d_in[3];
  const float* b3  = (const float*)d_in[4];
  const float* W2  = (const float*)d_in[5];
  const float* b2  = (const float*)d_in[6];
  const float* Wg  = (const float*)d_in[7];
  const float* bg  = (const float*)d_in[8];
  const float* Wf  = (const float*)d_in[9];
  const float* bfv = (const float*)d_in[10];
  float* out = (float*)d_out;

  char* p = (char*)d_ws;
  auto alloc = [&](size_t bytes) { char* r = p; p += (bytes + 255) & ~(size_t)255; return r; };
  unsigned short* Xb   = (unsigned short*)alloc((size_t)NTOK * DIM * 2);
  unsigned short* W13t = (unsigned short*)alloc((size_t)NE * 2 * HID * DIM * 2);
  unsigned short* W2t  = (unsigned short*)alloc((size_t)NE * OUTD * HID * 2);
  unsigned short* Wft  = (unsigned short*)alloc((size_t)OUTD * DIM * 2);
  unsigned short* hbuf = (unsigned short*)alloc((size_t)(NTOK * 2 + 256) * HID * 2);
  unsigned short* ob   = (unsigned short*)alloc((size_t)NTOK * 2 * OUTD * 2);
  int* topk_pack       = (int*)alloc(NTOK * 4);
  float* topk_w        = (float*)alloc(NTOK * 2 * 4);
  int* counts          = (int*)alloc(NE * 4);
  int* row_start       = (int*)alloc(NE * 4);
  int* tpA             = (int*)alloc((NE + 1) * 4);
  int* tpB             = (int*)alloc((NE + 1) * 4);
  int* blkcnt          = (int*)alloc(128 * NE * 4);
  int* list            = (int*)alloc(NTOK * 2 * 4);

  hipFuncSetAttribute((const void*)ffn_a_kernel,
                      hipFuncAttributeMaxDynamicSharedMemorySize, 131072);

  gating_kernel<<<128, 256, 0, stream>>>(X, Wg, bg, Xb, topk_pack, topk_w, blkcnt);
  tcast_i_kernel<<<dim3(HID / 32, DIM / 32, 16), 256, 0, stream>>>(W1, W3, W13t);
  tcast_kernel<<<dim3(OUTD / 32, HID / 32, NE), 256, 0, stream>>>(W2, W2t, HID, OUTD);
  tcast_kernel<<<dim3(OUTD / 32, DIM / 32, 1), 256, 0, stream>>>(Wf, Wft, DIM, OUTD);

  scatter_kernel<<<128, 64, 0, stream>>>(blkcnt, topk_pack, counts, row_start,
                                         tpA, tpB, list);

  // ffn_a: BM=256 -> max tiles = 32+7 = 39 -> 40
  ffn_a_kernel<<<dim3(2 * HID / 256, 40), 512, 131072, stream>>>(
      Xb, W13t, b1, b3, counts, row_start, tpA, list, hbuf);
  // ffn_b: BM=128 -> max tiles = 64+7 = 71 -> 72
  ffn_b_kernel<<<dim3(OUTD / 128, 72), 256, 0, stream>>>(
      hbuf, W2t, b2, counts, row_start, tpB, list, topk_w, ob);
  final_kernel<<<256, 256, 0, stream>>>(ob, Wft, bfv, out);
}